// Round 10
// baseline (212.345 us; speedup 1.0000x reference)
//
#include <hip/hip_runtime.h>
#include <hip/hip_bf16.h>
#include <math.h>

// Problem constants
#define N_  2
#define H_  8
#define G_  16      // N_*H_
#define L_  1024
#define S_  1024
#define E_  64
#define NC_ 6

typedef __attribute__((ext_vector_type(4))) float floatx4;
typedef __attribute__((ext_vector_type(8))) short short8;

#define MFMA16 __builtin_amdgcn_mfma_f32_16x16x32_bf16
#define L2E 1.4426950408889634f

#if __has_builtin(__builtin_amdgcn_exp2f)
#define EXP2(x) __builtin_amdgcn_exp2f(x)
#else
#define EXP2(x) __expf(0.6931471805599453f*(x))
#endif

// ---------------- workspace layout (bytes) ----------------
#define AHAT_OFF   0
#define AHAT_BYTES (NC_*G_*L_*128*2)          // 25,165,824
#define KHAT_OFF   (AHAT_OFF + AHAT_BYTES)
#define KHAT_BYTES (G_*S_*128*2)              //  4,194,304
#define PI_OFF     (KHAT_OFF + KHAT_BYTES)    // pi_t: [c][g][l] f32
#define PI_BYTES   (NC_*G_*L_*4)
#define HSQ_OFF    (PI_OFF + PI_BYTES)        // hsq: [c][g][l] f32
#define HSQ_BYTES  (NC_*G_*L_*4)
#define KSQ_OFF    (HSQ_OFF + HSQ_BYTES)      // ksq: [g][s] f32
#define KSQ_BYTES  (G_*S_*4)

// fast tanh: 1 - 2/(e^{2x}+1). Saturates correctly at +-inf; ~1e-7 rel err.
__device__ __forceinline__ float ftanh(float x) {
  return 1.0f - 2.0f * __builtin_amdgcn_rcpf(__expf(2.0f*x) + 1.0f);
}

// ---------------------------------------------------------------------------
// k_prep: merged htilde (768 blocks, scalar GEMM — Round-5 proven) + key (256)
// + pi (64). Non-k_main time (~88us) is harness-reset floor, invariant to
// prep structure (proven R10-R15). R18 change: per-code SCALE of stored
// htilde — Ahat0 x log2e, Ahat2 x 2log2e, Ahat4 x log2e (codes 1,3,5 raw) —
// so k_main can use raw exp2 (v_exp_f32) without the hidden per-exp multiply.
// hsq stays RAW |h|^2 (computed before scaling).
// ---------------------------------------------------------------------------
__global__ __launch_bounds__(256, 2) void k_prep(
    const float* __restrict__ q, const float* __restrict__ C,
    const float* __restrict__ key, const float* __restrict__ M,
    __hip_bfloat16* __restrict__ Ahat, float* __restrict__ hsq,
    __hip_bfloat16* __restrict__ Khat, float* __restrict__ ksq,
    float* __restrict__ pi_t) {
  extern __shared__ char smraw[];
  const int bx = blockIdx.x;
  const int t = threadIdx.x;

  if (bx < 768) {
    // ---------------- htilde part (q @ C, tanh, scale, bf16 hi/lo) --------
    float* qs = (float*)smraw;             // [128][68]
    float* Cs = qs + 128*68;               // [64][68]
    const int g = bx / 48, r6 = bx % 48, c = r6 >> 3, lch = r6 & 7;
    const int n = g >> 3, h = g & 7;
    const int l0 = lch * 128;
    const float scl = (c == 0 || c == 4) ? L2E : (c == 2) ? 2.0f*L2E : 1.0f;

    for (int u = t; u < 2048; u += 256) {          // q: 128 rows x 16 segs
      int row = u >> 4, seg = u & 15;
      *(float4*)(qs + row*68 + seg*4) =
        *(const float4*)(q + (((size_t)(n*L_ + l0 + row))*H_ + h)*E_ + seg*4);
    }
    for (int u = t; u < 1024; u += 256) {          // C[c][h]: 64 rows x 16 segs
      int e = u >> 4, seg = u & 15;
      *(float4*)(Cs + e*68 + seg*4) =
        *(const float4*)(C + (((size_t)(c*8 + h))*64 + e)*64 + seg*4);
    }
    __syncthreads();

    const int rg = t >> 3, fg = t & 7;  // 32 row-groups x 4 rows; 8 col-octets
    float acc[4][8];
    #pragma unroll
    for (int i = 0; i < 4; i++)
      #pragma unroll
      for (int j = 0; j < 8; j++) acc[i][j] = 0.0f;

    #pragma unroll 2
    for (int e0 = 0; e0 < 64; e0 += 4) {
      float4 q4[4];
      #pragma unroll
      for (int i = 0; i < 4; i++)
        q4[i] = *(const float4*)(qs + (rg*4 + i)*68 + e0);
      #pragma unroll
      for (int ee = 0; ee < 4; ee++) {
        float4 ca = *(const float4*)(Cs + (e0+ee)*68 + fg*8);
        float4 cb = *(const float4*)(Cs + (e0+ee)*68 + fg*8 + 4);
        float c8[8] = {ca.x, ca.y, ca.z, ca.w, cb.x, cb.y, cb.z, cb.w};
        #pragma unroll
        for (int i = 0; i < 4; i++) {
          float qv = (ee == 0) ? q4[i].x : (ee == 1) ? q4[i].y
                   : (ee == 2) ? q4[i].z : q4[i].w;
          #pragma unroll
          for (int j = 0; j < 8; j++) acc[i][j] = fmaf(qv, c8[j], acc[i][j]);
        }
      }
    }

    #pragma unroll
    for (int i = 0; i < 4; i++) {
      int l = l0 + rg*4 + i;
      size_t rowb = (((size_t)(c*G_ + g))*L_ + l) * 128;
      float ss = 0.0f;
      short8 hi8, lo8;
      #pragma unroll
      for (int j = 0; j < 8; j++) {
        float hv = ftanh(acc[i][j]);
        ss += hv*hv;                        // RAW |h|^2
        float hvs = hv * scl;               // per-code exp2-domain scale
        __hip_bfloat16 hi = __float2bfloat16(hvs);
        __hip_bfloat16 lo = __float2bfloat16(hvs - __bfloat162float(hi));
        short hs, ls;
        __builtin_memcpy(&hs, &hi, 2);
        __builtin_memcpy(&ls, &lo, 2);
        hi8[j] = hs; lo8[j] = ls;
      }
      *(short8*)((char*)Ahat + (rowb + fg*8)*2)      = hi8;
      *(short8*)((char*)Ahat + (rowb + 64 + fg*8)*2) = lo8;
      ss += __shfl_xor(ss, 1); ss += __shfl_xor(ss, 2); ss += __shfl_xor(ss, 4);
      if (fg == 0) hsq[((size_t)(c*G_ + g))*L_ + l] = ss;
    }
  } else if (bx < 1024) {
    // ---------------- key part: hi/lo split + ksq -------------------------
    const int kb = bx - 768;
    const int wv = t >> 6, lane = t & 63;
    #pragma unroll 2
    for (int it = 0; it < 16; it++) {
      int r = kb*64 + it*4 + wv;
      int kg = r >> 10, s = r & 1023, kn = kg >> 3, kh = kg & 7;
      float v = key[(((size_t)(kn*S_ + s))*H_ + kh)*E_ + lane];
      __hip_bfloat16 hi = __float2bfloat16(v);
      __hip_bfloat16 lo = __float2bfloat16(v - __bfloat162float(hi));
      size_t base = ((size_t)kg*S_ + s)*128;
      Khat[base + lane]      = hi;
      Khat[base + 64 + lane] = lo;
      float sq = v*v;
      #pragma unroll
      for (int off = 32; off; off >>= 1) sq += __shfl_xor(sq, off);
      if (lane == 0) ksq[(size_t)kg*S_ + s] = sq;
    }
  } else {
    // ---------------- pi part: softmax_k(q @ M[h]) ------------------------
    float* Ms = (float*)smraw;     // 384 f
    const int pb = bx - 1024;
    const int pg = pb >> 2, lch = pb & 3;
    const int pn = pg >> 3, ph = pg & 7;
    const int l = lch*256 + t;
    for (int u = t; u < 384; u += 256) Ms[u] = M[ph*384 + u];  // M[h][e][k]
    __syncthreads();
    const float* qrow = q + (((size_t)(pn*L_ + l))*H_ + ph)*E_;
    float p[6] = {0.f, 0.f, 0.f, 0.f, 0.f, 0.f};
    #pragma unroll 8
    for (int e = 0; e < 64; e++) {
      float qv = qrow[e];
      #pragma unroll
      for (int k = 0; k < 6; k++) p[k] = fmaf(qv, Ms[e*6 + k], p[k]);
    }
    float mx = p[0];
    #pragma unroll
    for (int k = 1; k < 6; k++) mx = fmaxf(mx, p[k]);
    float den = 0.f;
    #pragma unroll
    for (int k = 0; k < 6; k++) den += __expf(p[k] - mx);
    float rden = __builtin_amdgcn_rcpf(den);
    #pragma unroll
    for (int k = 0; k < 6; k++)
      pi_t[((size_t)(k*G_ + pg))*L_ + l] = __expf(p[k] - mx) * rden;
  }
}

// ---------------------------------------------------------------------------
// K4 — R18: R12/R14 structure EXACT (proven 112us best) + two surgical levers:
//  * exp2-domain folding: Ahat codes 0/2/4 pre-scaled by L2E/2L2E/L2E in prep;
//    constants folded (nh2l,h4hl,mvl,klogl) -> raw EXP2 (v_exp_f32, no hidden
//    mul per exp). Codes 1,3,5 keep raw d (c1 rcp denominator, c3 (d+1)^2,
//    c5 cos arg). ~5-7% VALU reduction + shorter Ev dependency chains.
//  * s_setprio(1) around each 6-MFMA cluster (T5): resident waves are from
//    DIFFERENT blocks, no barriers in sweeps -> attn-like regime (m191 +4-7%),
//    not lockstep-GEMM (m190 null).
// Refuted ledger (do NOT retry): phase-split acc[6] (R13 -4us), all-A-in-LDS
// (R11/R16 -17us), single-buffer K (R16), VGPR<=84 / launch_bounds 3 (R16:
// occupancy immovable at ~20%), wave tile-stagger + scalar prefetch (R17
// -4us, +12MB WRITE).
// ---------------------------------------------------------------------------
#define LDS_A6LO  0                      // 96 rows * 144 B = 13824 (lo halves)
#define LDS_ZRED  13824                  // 4*96 f = 1536
#define LDS_MRED  15360                  // 4*96 f = 1536
#define LDS_CST   16896                  // 96 float2 = 768
#define LDS_TOTAL 17664

__global__ __launch_bounds__(256, 2) void k_main(
    const __hip_bfloat16* __restrict__ Ahat, const __hip_bfloat16* __restrict__ Khat,
    const float* __restrict__ hsq, const float* __restrict__ ksq,
    const float* __restrict__ mask, const float* __restrict__ klen,
    const float* __restrict__ pi_t, float* __restrict__ out) {
  extern __shared__ char smraw[];
  char*   A6     = smraw + LDS_A6LO;
  float*  zred   = (float*)(smraw + LDS_ZRED);
  float*  mred   = (float*)(smraw + LDS_MRED);
  float2* cst    = (float2*)(smraw + LDS_CST);

  const int l0 = blockIdx.x * 16; const int g = blockIdx.y; const int n = g >> 3;
  const int t = threadIdx.x; const int w = t >> 6; const int lane = t & 63;
  const int quad = lane >> 4; const int lc = lane & 15;

  // ---- stage A6 lo-halves once: 96 rows x 128B payload, stride 144 ----
  #pragma unroll
  for (int rep = 0; rep < 3; rep++) {
    int u = t + rep*256; int row = u >> 3, seg = u & 7;   // row 0..95
    int cc = row >> 4, lr = row & 15;
    *(int4*)(A6 + row*144 + seg*16) =
      *(const int4*)((const char*)Ahat +
          (((size_t)(cc*G_ + g))*L_ + l0 + lr)*256 + 128 + seg*16);
  }

  // ---- htilde HI fragments in registers: 6 codes x 2 chunks (48 VGPR) ----
  short8 ah[6][2];
  #pragma unroll
  for (int cc = 0; cc < 6; cc++) {
    const char* arow = (const char*)Ahat + (((size_t)(cc*G_ + g))*L_ + l0 + lc)*256;
    ah[cc][0] = *(const short8*)(arow + quad*16);
    ah[cc][1] = *(const short8*)(arow + 64 + quad*16);
  }

  // per-lane constants (one l = l0+lc per lane)
  float h1p  = 1.0f + hsq[((size_t)(1*G_ + g))*L_ + l0 + lc];          // c1 raw
  float nh2l = (64.0f - hsq[((size_t)(2*G_ + g))*L_ + l0 + lc]) * L2E; // c2 log2
  float h4hl = -0.5f * hsq[((size_t)(4*G_ + g))*L_ + l0 + lc] * L2E;   // c4 log2
  float nh5  = -hsq[((size_t)(5*G_ + g))*L_ + l0 + lc];                // c5 raw

  __syncthreads();                       // A6 lo staged

  // K-fragment loader (A operand; 4 x 16B from global, L2-resident)
  auto LOADK = [&](int st, short8 (&bf)[4]) {
    const char* base = (const char*)Khat +
        (((size_t)g)*S_ + st*64 + w*16 + lc)*256 + quad*16;
    #pragma unroll
    for (int kt = 0; kt < 4; kt++)
      bf[kt] = *(const short8*)(base + kt*64);
  };

  // Flat Z: Zc0..3={L,O,R,W}, zp=P(shifted). Online: (m3,z3)=Y. Lane-scalar.
  float Zc0 = 0.f, Zc1 = 0.f, Zc2 = 0.f, Zc3 = 0.f, zp = 0.f;
  float m3 = -INFINITY, z3 = 0.f;

  // ================= sweep 1: Z =================
  auto SWEEP1 = [&](int st, const short8 (&bf)[4]) {
    int sb = st*64 + w*16 + quad*4;      // lane's 4 consecutive s
    float4 mk4 = *(const float4*)(mask + ((size_t)(n*L_ + l0 + lc))*S_ + sb);
    float4 kl4 = *(const float4*)(klen + (size_t)n*S_ + sb);
    float4 kq4 = *(const float4*)(ksq  + (size_t)g*S_ + sb);
    float kq[4] = {kq4.x, kq4.y, kq4.z, kq4.w};
    float mv[4], mvl[4], Ev[4], pcl[4], rcl[4], wcr[4];
    mv[0] = mk4.x + kl4.x; mv[1] = mk4.y + kl4.y;
    mv[2] = mk4.z + kl4.z; mv[3] = mk4.w + kl4.w;
    #pragma unroll
    for (int i = 0; i < 4; i++) {
      mvl[i] = mv[i] * L2E;
      Ev[i]  = EXP2(mvl[i]);                       // c1 only
      float klogl = kq[i] * L2E;
      pcl[i] = nh2l - klogl + mvl[i];              // c2 folded constant
      rcl[i] = fmaf(-0.5f, klogl, h4hl);           // c4 inner constant
      wcr[i] = nh5 - kq[i];                        // c5 raw constant
    }
    #pragma unroll
    for (int c = 0; c < 6; c++) {
      short8 al0 = *(const short8*)(A6 + (c*16 + lc)*144 + quad*16);
      short8 al1 = *(const short8*)(A6 + (c*16 + lc)*144 + 64 + quad*16);
      floatx4 a = {0.f, 0.f, 0.f, 0.f};
      __builtin_amdgcn_s_setprio(1);
      a = MFMA16(bf[0], ah[c][0], a, 0,0,0);   // Khi x Hhi (k0-31)
      a = MFMA16(bf[1], ah[c][1], a, 0,0,0);   // Khi x Hhi (k32-63)
      a = MFMA16(bf[0], al0,      a, 0,0,0);   // Khi x Hlo
      a = MFMA16(bf[1], al1,      a, 0,0,0);
      a = MFMA16(bf[2], ah[c][0], a, 0,0,0);   // Klo x Hhi
      a = MFMA16(bf[3], ah[c][1], a, 0,0,0);
      __builtin_amdgcn_s_setprio(0);
      #pragma unroll
      for (int i = 0; i < 4; i++) {
        float d = a[i];
        if (c == 0) {                            // d pre-scaled by L2E
          Zc0 += EXP2(d + mvl[i]);
        } else if (c == 1) {                     // d raw
          Zc1 = fmaf(Ev[i], __builtin_amdgcn_rcpf(fmaf(-2.f, d, h1p + kq[i])), Zc1);
        } else if (c == 2) {                     // d pre-scaled by 2*L2E
          zp += EXP2(d + pcl[i]);
        } else if (c == 3) {                     // Y online, raw domain
          float tt = d + 1.f;
          float x  = fmaf(tt, tt, mv[i]);
          float mn = fmaxf(m3, x);
          float e  = __expf(fminf(m3, x) - mn);
          z3 = (x > m3) ? fmaf(z3, e, 1.0f) : (z3 + e);
          m3 = mn;
        } else if (c == 4) {                     // d pre-scaled by L2E
          float inner = EXP2(d + rcl[i]);        // = exp(d_raw - 0.5*ns)
          Zc2 += EXP2(fmaf(inner, L2E, mvl[i]));
        } else {                                 // d raw
          float a5 = fmaf(2.f, d, wcr[i]);
          float wv = __cosf(a5) * __expf(a5);
          Zc3 += EXP2(fmaf(wv, L2E, mvl[i]));
        }
      }
    }
  };

  {
    short8 bA[4], bB[4];
    LOADK(0, bA);
    #pragma unroll 1
    for (int st = 0; st < 16; st += 2) {
      LOADK(st + 1, bB);
      SWEEP1(st, bA);
      LOADK((st + 2) & 15, bA);
      SWEEP1(st + 1, bB);
    }
  }

  // ---- fold across quads (lanes lc, lc+16, lc+32, lc+48) ----
  #pragma unroll
  for (int off = 16; off < 64; off <<= 1) {
    Zc0 += __shfl_xor(Zc0, off); Zc1 += __shfl_xor(Zc1, off);
    Zc2 += __shfl_xor(Zc2, off); Zc3 += __shfl_xor(Zc3, off);
    zp  += __shfl_xor(zp,  off);
    float mo = __shfl_xor(m3, off);
    float zo = __shfl_xor(z3, off);
    float mn = fmaxf(m3, mo);
    float e  = __expf(fminf(m3, mo) - mn);
    z3 = (mo > m3) ? fmaf(z3, e, zo) : fmaf(zo, e, z3);
    m3 = mn;
  }
  if (lane < 16) {                       // quad 0 holds wave totals per l=lc
    zred[w*96 + 0*16 + lc] = Zc0; mred[w*96 + 0*16 + lc] = 0.f;
    zred[w*96 + 1*16 + lc] = Zc1; mred[w*96 + 1*16 + lc] = 0.f;
    zred[w*96 + 2*16 + lc] = zp;  mred[w*96 + 2*16 + lc] = 0.f;
    zred[w*96 + 3*16 + lc] = z3;  mred[w*96 + 3*16 + lc] = m3;
    zred[w*96 + 4*16 + lc] = Zc2; mred[w*96 + 4*16 + lc] = 0.f;
    zred[w*96 + 5*16 + lc] = Zc3; mred[w*96 + 5*16 + lc] = 0.f;
  }
  __syncthreads();
  if (t < 96) {
    int c = t >> 4;
    float z = zred[t], m = mred[t];
    if (c == 3) {
      #pragma unroll
      for (int w2 = 1; w2 < 4; w2++) {
        float mo = mred[w2*96 + t], zo = zred[w2*96 + t];
        float mn = fmaxf(m, mo);
        float e  = __expf(fminf(m, mo) - mn);
        z = (mo > m) ? fmaf(z, e, zo) : fmaf(zo, e, z);
        m = mn;
      }
    } else {
      #pragma unroll
      for (int w2 = 1; w2 < 4; w2++) z += zred[w2*96 + t];
    }
    float piv = pi_t[((size_t)((t >> 4)*G_ + g))*L_ + l0 + (t & 15)];
    cst[t] = make_float2(piv / z, m);
  }
  __syncthreads();

  float ac0 = cst[0*16 + lc].x, ac1 = cst[1*16 + lc].x, ac2 = cst[2*16 + lc].x;
  float ac3 = cst[3*16 + lc].x, ac4 = cst[4*16 + lc].x, ac5 = cst[5*16 + lc].x;
  float m3f = cst[3*16 + lc].y;

  // ================= sweep 2: emit =================
  auto SWEEP2 = [&](int st, const short8 (&bf)[4]) {
    int sb = st*64 + w*16 + quad*4;
    float4 mk4 = *(const float4*)(mask + ((size_t)(n*L_ + l0 + lc))*S_ + sb);
    float4 kl4 = *(const float4*)(klen + (size_t)n*S_ + sb);
    float4 kq4 = *(const float4*)(ksq  + (size_t)g*S_ + sb);
    float kq[4] = {kq4.x, kq4.y, kq4.z, kq4.w};
    float mv[4], mvl[4], ac1E[4], pcl[4], rcl[4], wcr[4];
    mv[0] = mk4.x + kl4.x; mv[1] = mk4.y + kl4.y;
    mv[2] = mk4.z + kl4.z; mv[3] = mk4.w + kl4.w;
    #pragma unroll
    for (int i = 0; i < 4; i++) {
      mvl[i]  = mv[i] * L2E;
      ac1E[i] = ac1 * EXP2(mvl[i]);                // c1's Ev folded into coef
      float klogl = kq[i] * L2E;
      pcl[i] = nh2l - klogl + mvl[i];
      rcl[i] = fmaf(-0.5f, klogl, h4hl);
      wcr[i] = nh5 - kq[i];
    }
    float Gg[4] = {0.f, 0.f, 0.f, 0.f};
    #pragma unroll
    for (int c = 0; c < 6; c++) {
      short8 al0 = *(const short8*)(A6 + (c*16 + lc)*144 + quad*16);
      short8 al1 = *(const short8*)(A6 + (c*16 + lc)*144 + 64 + quad*16);
      floatx4 a = {0.f, 0.f, 0.f, 0.f};
      __builtin_amdgcn_s_setprio(1);
      a = MFMA16(bf[0], ah[c][0], a, 0,0,0);
      a = MFMA16(bf[1], ah[c][1], a, 0,0,0);
      a = MFMA16(bf[0], al0,      a, 0,0,0);
      a = MFMA16(bf[1], al1,      a, 0,0,0);
      a = MFMA16(bf[2], ah[c][0], a, 0,0,0);
      a = MFMA16(bf[3], ah[c][1], a, 0,0,0);
      __builtin_amdgcn_s_setprio(0);
      #pragma unroll
      for (int i = 0; i < 4; i++) {
        float d = a[i];
        if (c == 0) {
          Gg[i] = fmaf(ac0, EXP2(d + mvl[i]), Gg[i]);
        } else if (c == 1) {
          Gg[i] = fmaf(ac1E[i],
              __builtin_amdgcn_rcpf(fmaf(-2.f, d, h1p + kq[i])), Gg[i]);
        } else if (c == 2) {
          Gg[i] = fmaf(ac2, EXP2(d + pcl[i]), Gg[i]);
        } else if (c == 3) {
          float tt = d + 1.f;
          float x  = fmaf(tt, tt, mv[i]);
          Gg[i] = fmaf(ac3, __expf(x - m3f), Gg[i]);
        } else if (c == 4) {
          float inner = EXP2(d + rcl[i]);
          Gg[i] = fmaf(ac4, EXP2(fmaf(inner, L2E, mvl[i])), Gg[i]);
        } else {
          float a5 = fmaf(2.f, d, wcr[i]);
          float wv = __cosf(a5) * __expf(a5);
          Gg[i] = fmaf(ac5, EXP2(fmaf(wv, L2E, mvl[i])), Gg[i]);
        }
      }
    }
    float4 ov;
    ov.x = Gg[0]; ov.y = Gg[1]; ov.z = Gg[2]; ov.w = Gg[3];
    *(float4*)(out + (((size_t)g)*L_ + l0 + lc)*S_ + sb) = ov;
  };

  {
    short8 bA[4], bB[4];
    LOADK(0, bA);
    #pragma unroll 1
    for (int st = 0; st < 16; st += 2) {
      LOADK(st + 1, bB);
      SWEEP2(st, bA);
      LOADK((st + 2) & 15, bA);
      SWEEP2(st + 1, bB);
    }
  }
}

// ---------------------------------------------------------------------------
extern "C" void kernel_launch(void* const* d_in, const int* in_sizes, int n_in,
                              void* d_out, int out_size, void* d_ws, size_t ws_size,
                              hipStream_t stream) {
  (void)in_sizes; (void)n_in; (void)out_size; (void)ws_size;
  const float* q    = (const float*)d_in[0];
  const float* key  = (const float*)d_in[1];
  const float* mask = (const float*)d_in[2];
  const float* klen = (const float*)d_in[3];
  const float* M    = (const float*)d_in[4];
  const float* C    = (const float*)d_in[5];
  char* ws = (char*)d_ws;
  __hip_bfloat16* Ahat = (__hip_bfloat16*)(ws + AHAT_OFF);
  __hip_bfloat16* Khat = (__hip_bfloat16*)(ws + KHAT_OFF);
  float* pi_t    = (float*)(ws + PI_OFF);
  float* hsq     = (float*)(ws + HSQ_OFF);
  float* ksq     = (float*)(ws + KSQ_OFF);
  float* out = (float*)d_out;

  k_prep<<<1088, 256, 52224, stream>>>(q, C, key, M, Ahat, hsq, Khat, ksq, pi_t);
  k_main<<<dim3(64, 16), 256, LDS_TOTAL, stream>>>(Ahat, Khat, hsq, ksq, mask, klen,
                                                   pi_t, out);
}

// Round 11
// 195.874 us; speedup vs baseline: 1.0841x; 1.0841x over previous
//
#include <hip/hip_runtime.h>
#include <hip/hip_bf16.h>
#include <math.h>

// Problem constants
#define N_  2
#define H_  8
#define G_  16      // N_*H_
#define L_  1024
#define S_  1024
#define E_  64
#define NC_ 6

typedef __attribute__((ext_vector_type(4))) float floatx4;
typedef __attribute__((ext_vector_type(8))) short short8;

#define MFMA16 __builtin_amdgcn_mfma_f32_16x16x32_bf16

// ---------------- workspace layout (bytes) ----------------
#define AHAT_OFF   0
#define AHAT_BYTES (NC_*G_*L_*128*2)          // 25,165,824
#define KHAT_OFF   (AHAT_OFF + AHAT_BYTES)
#define KHAT_BYTES (G_*S_*128*2)              //  4,194,304
#define PI_OFF     (KHAT_OFF + KHAT_BYTES)    // pi_t: [c][g][l] f32
#define PI_BYTES   (NC_*G_*L_*4)
#define HSQ_OFF    (PI_OFF + PI_BYTES)        // hsq: [c][g][l] f32
#define HSQ_BYTES  (NC_*G_*L_*4)
#define KSQ_OFF    (HSQ_OFF + HSQ_BYTES)      // ksq: [g][s] f32
#define KSQ_BYTES  (G_*S_*4)

// fast tanh: 1 - 2/(e^{2x}+1). Saturates correctly at +-inf; ~1e-7 rel err.
__device__ __forceinline__ float ftanh(float x) {
  return 1.0f - 2.0f * __builtin_amdgcn_rcpf(__expf(2.0f*x) + 1.0f);
}

// ---------------------------------------------------------------------------
// k_prep: merged htilde (768 blocks) + key (256) + pi (64).
// Session-best prep (R14/Round-5 measured 199.576 total). Non-k_main time
// (~88us) is harness-reset floor — invariant to prep structure (3 rewrites,
// 4/2/1 launches, R10-R15). Do not attack prep further.
// ---------------------------------------------------------------------------
__global__ __launch_bounds__(256, 2) void k_prep(
    const float* __restrict__ q, const float* __restrict__ C,
    const float* __restrict__ key, const float* __restrict__ M,
    __hip_bfloat16* __restrict__ Ahat, float* __restrict__ hsq,
    __hip_bfloat16* __restrict__ Khat, float* __restrict__ ksq,
    float* __restrict__ pi_t) {
  extern __shared__ char smraw[];
  const int bx = blockIdx.x;
  const int t = threadIdx.x;

  if (bx < 768) {
    // ---------------- htilde part (q @ C, tanh, bf16 hi/lo, |h|^2) --------
    float* qs = (float*)smraw;             // [128][68]
    float* Cs = qs + 128*68;               // [64][68]
    const int g = bx / 48, r6 = bx % 48, c = r6 >> 3, lch = r6 & 7;
    const int n = g >> 3, h = g & 7;
    const int l0 = lch * 128;

    for (int u = t; u < 2048; u += 256) {          // q: 128 rows x 16 segs
      int row = u >> 4, seg = u & 15;
      *(float4*)(qs + row*68 + seg*4) =
        *(const float4*)(q + (((size_t)(n*L_ + l0 + row))*H_ + h)*E_ + seg*4);
    }
    for (int u = t; u < 1024; u += 256) {          // C[c][h]: 64 rows x 16 segs
      int e = u >> 4, seg = u & 15;
      *(float4*)(Cs + e*68 + seg*4) =
        *(const float4*)(C + (((size_t)(c*8 + h))*64 + e)*64 + seg*4);
    }
    __syncthreads();

    const int rg = t >> 3, fg = t & 7;  // 32 row-groups x 4 rows; 8 col-octets
    float acc[4][8];
    #pragma unroll
    for (int i = 0; i < 4; i++)
      #pragma unroll
      for (int j = 0; j < 8; j++) acc[i][j] = 0.0f;

    #pragma unroll 2
    for (int e0 = 0; e0 < 64; e0 += 4) {
      float4 q4[4];
      #pragma unroll
      for (int i = 0; i < 4; i++)
        q4[i] = *(const float4*)(qs + (rg*4 + i)*68 + e0);
      #pragma unroll
      for (int ee = 0; ee < 4; ee++) {
        float4 ca = *(const float4*)(Cs + (e0+ee)*68 + fg*8);
        float4 cb = *(const float4*)(Cs + (e0+ee)*68 + fg*8 + 4);
        float c8[8] = {ca.x, ca.y, ca.z, ca.w, cb.x, cb.y, cb.z, cb.w};
        #pragma unroll
        for (int i = 0; i < 4; i++) {
          float qv = (ee == 0) ? q4[i].x : (ee == 1) ? q4[i].y
                   : (ee == 2) ? q4[i].z : q4[i].w;
          #pragma unroll
          for (int j = 0; j < 8; j++) acc[i][j] = fmaf(qv, c8[j], acc[i][j]);
        }
      }
    }

    #pragma unroll
    for (int i = 0; i < 4; i++) {
      int l = l0 + rg*4 + i;
      size_t rowb = (((size_t)(c*G_ + g))*L_ + l) * 128;
      float ss = 0.0f;
      short8 hi8, lo8;
      #pragma unroll
      for (int j = 0; j < 8; j++) {
        float hv = ftanh(acc[i][j]);
        ss += hv*hv;
        __hip_bfloat16 hi = __float2bfloat16(hv);
        __hip_bfloat16 lo = __float2bfloat16(hv - __bfloat162float(hi));
        short hs, ls;
        __builtin_memcpy(&hs, &hi, 2);
        __builtin_memcpy(&ls, &lo, 2);
        hi8[j] = hs; lo8[j] = ls;
      }
      *(short8*)((char*)Ahat + (rowb + fg*8)*2)      = hi8;
      *(short8*)((char*)Ahat + (rowb + 64 + fg*8)*2) = lo8;
      ss += __shfl_xor(ss, 1); ss += __shfl_xor(ss, 2); ss += __shfl_xor(ss, 4);
      if (fg == 0) hsq[((size_t)(c*G_ + g))*L_ + l] = ss;
    }
  } else if (bx < 1024) {
    // ---------------- key part: hi/lo split + ksq -------------------------
    const int kb = bx - 768;
    const int wv = t >> 6, lane = t & 63;
    #pragma unroll 2
    for (int it = 0; it < 16; it++) {
      int r = kb*64 + it*4 + wv;
      int g = r >> 10, s = r & 1023, n = g >> 3, h = g & 7;
      float v = key[(((size_t)(n*S_ + s))*H_ + h)*E_ + lane];
      __hip_bfloat16 hi = __float2bfloat16(v);
      __hip_bfloat16 lo = __float2bfloat16(v - __bfloat162float(hi));
      size_t base = ((size_t)g*S_ + s)*128;
      Khat[base + lane]      = hi;
      Khat[base + 64 + lane] = lo;
      float sq = v*v;
      #pragma unroll
      for (int off = 32; off; off >>= 1) sq += __shfl_xor(sq, off);
      if (lane == 0) ksq[(size_t)g*S_ + s] = sq;
    }
  } else {
    // ---------------- pi part: softmax_k(q @ M[h]) ------------------------
    float* Ms = (float*)smraw;     // 384 f
    const int pb = bx - 1024;
    const int g = pb >> 2, lch = pb & 3;
    const int n = g >> 3, h = g & 7;
    const int l = lch*256 + t;
    for (int u = t; u < 384; u += 256) Ms[u] = M[h*384 + u];  // M[h][e][k]
    __syncthreads();
    const float* qrow = q + (((size_t)(n*L_ + l))*H_ + h)*E_;
    float p[6] = {0.f, 0.f, 0.f, 0.f, 0.f, 0.f};
    #pragma unroll 8
    for (int e = 0; e < 64; e++) {
      float qv = qrow[e];
      #pragma unroll
      for (int k = 0; k < 6; k++) p[k] = fmaf(qv, Ms[e*6 + k], p[k]);
    }
    float mx = p[0];
    #pragma unroll
    for (int k = 1; k < 6; k++) mx = fmaxf(mx, p[k]);
    float den = 0.f;
    #pragma unroll
    for (int k = 0; k < 6; k++) den += __expf(p[k] - mx);
    float rden = __builtin_amdgcn_rcpf(den);
    #pragma unroll
    for (int k = 0; k < 6; k++)
      pi_t[((size_t)(k*G_ + g))*L_ + l] = __expf(p[k] - mx) * rden;
  }
}

// ---------------------------------------------------------------------------
// K4: fused stats+emit — R12/R14 structure, SESSION BEST (112.2us measured).
// Transposed MFMA d[s][l] = K x H; lane owns one l (=lc); hi frags codes 0-5
// in regs (48 VGPR), lo halves in LDS (144-stride); 2-deep K prefetch from
// global (L2-resident).
// REFUTED LEDGER — do NOT retry any of these (all measured worse):
//  * no-LDS / all-global A-frags            R10: 140us (latency, 2 w/SIMD)
//  * ALL A-frags in LDS (272-stride)        R11/R16: 129us (LDS pipe)
//  * phase-split acc[6] MFMA-then-VALU      R13: 117us (compiler already
//    interleaves codes; manual split adds pressure)
//  * VGPR<=84 + launch_bounds(256,3)        R16: 129us, occupancy STILL ~20%
//    (register-pool wall invisible to VGPR count; occupancy immovable)
//  * wave tile-stagger + scalar prefetch    R17: 116us (+12MB WRITE, worse
//    coalescing; convoy theory refuted)
//  * exp2-domain folding + s_setprio pair   R18: 124us (setprio fences the
//    scheduler: bank conflicts 393K->6.29M; exp2-ALONE remains unmeasured)
// Plateau diagnosis: latency-bound at VALU 48% / MFMA 28% / HBM 12%,
// occupancy pinned ~20%. Compiler's default schedule beats all manual
// reorderings tried.
// ---------------------------------------------------------------------------
#define LDS_A6LO  0                      // 96 rows * 144 B = 13824 (lo halves)
#define LDS_ZRED  13824                  // 4*96 f = 1536
#define LDS_MRED  15360                  // 4*96 f = 1536
#define LDS_CST   16896                  // 96 float2 = 768
#define LDS_TOTAL 17664

__global__ __launch_bounds__(256, 2) void k_main(
    const __hip_bfloat16* __restrict__ Ahat, const __hip_bfloat16* __restrict__ Khat,
    const float* __restrict__ hsq, const float* __restrict__ ksq,
    const float* __restrict__ mask, const float* __restrict__ klen,
    const float* __restrict__ pi_t, float* __restrict__ out) {
  extern __shared__ char smraw[];
  char*   A6     = smraw + LDS_A6LO;
  float*  zred   = (float*)(smraw + LDS_ZRED);
  float*  mred   = (float*)(smraw + LDS_MRED);
  float2* cst    = (float2*)(smraw + LDS_CST);

  const int l0 = blockIdx.x * 16; const int g = blockIdx.y; const int n = g >> 3;
  const int t = threadIdx.x; const int w = t >> 6; const int lane = t & 63;
  const int quad = lane >> 4; const int lc = lane & 15;

  // ---- stage A6 lo-halves once: 96 rows x 128B payload, stride 144 ----
  #pragma unroll
  for (int rep = 0; rep < 3; rep++) {
    int u = t + rep*256; int row = u >> 3, seg = u & 7;   // row 0..95
    int cc = row >> 4, lr = row & 15;
    *(int4*)(A6 + row*144 + seg*16) =
      *(const int4*)((const char*)Ahat +
          (((size_t)(cc*G_ + g))*L_ + l0 + lr)*256 + 128 + seg*16);
  }

  // ---- htilde HI fragments in registers: 6 codes x 2 chunks (48 VGPR) ----
  short8 ah[6][2];
  #pragma unroll
  for (int cc = 0; cc < 6; cc++) {
    const char* arow = (const char*)Ahat + (((size_t)(cc*G_ + g))*L_ + l0 + lc)*256;
    ah[cc][0] = *(const short8*)(arow + quad*16);
    ah[cc][1] = *(const short8*)(arow + 64 + quad*16);
  }

  // per-lane constants (one l = l0+lc per lane)
  float h1p = 1.0f  + hsq[((size_t)(1*G_ + g))*L_ + l0 + lc];
  float nh2 = 64.0f - hsq[((size_t)(2*G_ + g))*L_ + l0 + lc];   // P: +64 shift
  float h4h = -0.5f * hsq[((size_t)(4*G_ + g))*L_ + l0 + lc];
  float nh5 = -hsq[((size_t)(5*G_ + g))*L_ + l0 + lc];

  __syncthreads();                       // A6 lo staged

  // K-fragment loader (A operand; 4 x 16B from global, L2-resident)
  auto LOADK = [&](int st, short8 (&bf)[4]) {
    const char* base = (const char*)Khat +
        (((size_t)g)*S_ + st*64 + w*16 + lc)*256 + quad*16;
    #pragma unroll
    for (int kt = 0; kt < 4; kt++)
      bf[kt] = *(const short8*)(base + kt*64);
  };

  // Flat Z: Zc0..3={L,O,R,W}, zp=P(shifted). Online: (m3,z3)=Y. Lane-scalar.
  float Zc0 = 0.f, Zc1 = 0.f, Zc2 = 0.f, Zc3 = 0.f, zp = 0.f;
  float m3 = -INFINITY, z3 = 0.f;

  // ================= sweep 1: Z =================
  auto SWEEP1 = [&](int st, const short8 (&bf)[4]) {
    int sb = st*64 + w*16 + quad*4;      // lane's 4 consecutive s
    float4 mk4 = *(const float4*)(mask + ((size_t)(n*L_ + l0 + lc))*S_ + sb);
    float4 kl4 = *(const float4*)(klen + (size_t)n*S_ + sb);
    float4 kq4 = *(const float4*)(ksq  + (size_t)g*S_ + sb);
    float kq[4] = {kq4.x, kq4.y, kq4.z, kq4.w};
    float mv[4], Ev[4];
    mv[0] = mk4.x + kl4.x; mv[1] = mk4.y + kl4.y;
    mv[2] = mk4.z + kl4.z; mv[3] = mk4.w + kl4.w;
    #pragma unroll
    for (int i = 0; i < 4; i++) Ev[i] = __expf(mv[i]);
    #pragma unroll
    for (int c = 0; c < 6; c++) {
      short8 al0 = *(const short8*)(A6 + (c*16 + lc)*144 + quad*16);
      short8 al1 = *(const short8*)(A6 + (c*16 + lc)*144 + 64 + quad*16);
      floatx4 a = {0.f, 0.f, 0.f, 0.f};
      a = MFMA16(bf[0], ah[c][0], a, 0,0,0);   // Khi x Hhi (k0-31)
      a = MFMA16(bf[1], ah[c][1], a, 0,0,0);   // Khi x Hhi (k32-63)
      a = MFMA16(bf[0], al0,      a, 0,0,0);   // Khi x Hlo
      a = MFMA16(bf[1], al1,      a, 0,0,0);
      a = MFMA16(bf[2], ah[c][0], a, 0,0,0);   // Klo x Hhi
      a = MFMA16(bf[3], ah[c][1], a, 0,0,0);
      #pragma unroll
      for (int i = 0; i < 4; i++) {
        float d = a[i];
        if (c == 0) {
          Zc0 = fmaf(Ev[i], __expf(d), Zc0);
        } else if (c == 1) {
          Zc1 = fmaf(Ev[i], __builtin_amdgcn_rcpf(fmaf(-2.f, d, h1p + kq[i])), Zc1);
        } else if (c == 2) {                              // P flat, shifted
          zp += __expf(fmaf(2.f, d, nh2 - kq[i] + mv[i]));
        } else if (c == 3) {                              // Y online
          float tt = d + 1.f;
          float x  = fmaf(tt, tt, mv[i]);
          float mn = fmaxf(m3, x);
          float e  = __expf(fminf(m3, x) - mn);
          z3 = (x > m3) ? fmaf(z3, e, 1.0f) : (z3 + e);
          m3 = mn;
        } else if (c == 4) {
          Zc2 = fmaf(Ev[i], __expf(__expf(d + fmaf(-0.5f, kq[i], h4h))), Zc2);
        } else {
          float a5 = fmaf(2.f, d, nh5 - kq[i]);
          Zc3 = fmaf(Ev[i], __expf(__cosf(a5) * __expf(a5)), Zc3);
        }
      }
    }
  };

  {
    short8 bA[4], bB[4];
    LOADK(0, bA);
    #pragma unroll 1
    for (int st = 0; st < 16; st += 2) {
      LOADK(st + 1, bB);
      SWEEP1(st, bA);
      LOADK((st + 2) & 15, bA);
      SWEEP1(st + 1, bB);
    }
  }

  // ---- fold across quads (lanes lc, lc+16, lc+32, lc+48) ----
  #pragma unroll
  for (int off = 16; off < 64; off <<= 1) {
    Zc0 += __shfl_xor(Zc0, off); Zc1 += __shfl_xor(Zc1, off);
    Zc2 += __shfl_xor(Zc2, off); Zc3 += __shfl_xor(Zc3, off);
    zp  += __shfl_xor(zp,  off);
    float mo = __shfl_xor(m3, off);
    float zo = __shfl_xor(z3, off);
    float mn = fmaxf(m3, mo);
    float e  = __expf(fminf(m3, mo) - mn);
    z3 = (mo > m3) ? fmaf(z3, e, zo) : fmaf(zo, e, z3);
    m3 = mn;
  }
  if (lane < 16) {                       // quad 0 holds wave totals per l=lc
    zred[w*96 + 0*16 + lc] = Zc0; mred[w*96 + 0*16 + lc] = 0.f;
    zred[w*96 + 1*16 + lc] = Zc1; mred[w*96 + 1*16 + lc] = 0.f;
    zred[w*96 + 2*16 + lc] = zp;  mred[w*96 + 2*16 + lc] = 0.f;
    zred[w*96 + 3*16 + lc] = z3;  mred[w*96 + 3*16 + lc] = m3;
    zred[w*96 + 4*16 + lc] = Zc2; mred[w*96 + 4*16 + lc] = 0.f;
    zred[w*96 + 5*16 + lc] = Zc3; mred[w*96 + 5*16 + lc] = 0.f;
  }
  __syncthreads();
  if (t < 96) {
    int c = t >> 4;
    float z = zred[t], m = mred[t];
    if (c == 3) {
      #pragma unroll
      for (int w2 = 1; w2 < 4; w2++) {
        float mo = mred[w2*96 + t], zo = zred[w2*96 + t];
        float mn = fmaxf(m, mo);
        float e  = __expf(fminf(m, mo) - mn);
        z = (mo > m) ? fmaf(z, e, zo) : fmaf(zo, e, z);
        m = mn;
      }
    } else {
      #pragma unroll
      for (int w2 = 1; w2 < 4; w2++) z += zred[w2*96 + t];
    }
    float piv = pi_t[((size_t)((t >> 4)*G_ + g))*L_ + l0 + (t & 15)];
    cst[t] = make_float2(piv / z, m);
  }
  __syncthreads();

  float ac0 = cst[0*16 + lc].x, ac1 = cst[1*16 + lc].x, ac2 = cst[2*16 + lc].x;
  float ac3 = cst[3*16 + lc].x, ac4 = cst[4*16 + lc].x, ac5 = cst[5*16 + lc].x;
  float m3f = cst[3*16 + lc].y;

  // ================= sweep 2: emit =================
  auto SWEEP2 = [&](int st, const short8 (&bf)[4]) {
    int sb = st*64 + w*16 + quad*4;
    float4 mk4 = *(const float4*)(mask + ((size_t)(n*L_ + l0 + lc))*S_ + sb);
    float4 kl4 = *(const float4*)(klen + (size_t)n*S_ + sb);
    float4 kq4 = *(const float4*)(ksq  + (size_t)g*S_ + sb);
    float kq[4] = {kq4.x, kq4.y, kq4.z, kq4.w};
    float mv[4], Ev[4];
    mv[0] = mk4.x + kl4.x; mv[1] = mk4.y + kl4.y;
    mv[2] = mk4.z + kl4.z; mv[3] = mk4.w + kl4.w;
    #pragma unroll
    for (int i = 0; i < 4; i++) Ev[i] = __expf(mv[i]);
    float Sacc[4] = {0.f, 0.f, 0.f, 0.f};   // Ev-scaled flat codes (L,O,R,W)
    float Gg[4]   = {0.f, 0.f, 0.f, 0.f};   // P (mv folded) + Y
    #pragma unroll
    for (int c = 0; c < 6; c++) {
      short8 al0 = *(const short8*)(A6 + (c*16 + lc)*144 + quad*16);
      short8 al1 = *(const short8*)(A6 + (c*16 + lc)*144 + 64 + quad*16);
      floatx4 a = {0.f, 0.f, 0.f, 0.f};
      a = MFMA16(bf[0], ah[c][0], a, 0,0,0);
      a = MFMA16(bf[1], ah[c][1], a, 0,0,0);
      a = MFMA16(bf[0], al0,      a, 0,0,0);
      a = MFMA16(bf[1], al1,      a, 0,0,0);
      a = MFMA16(bf[2], ah[c][0], a, 0,0,0);
      a = MFMA16(bf[3], ah[c][1], a, 0,0,0);
      #pragma unroll
      for (int i = 0; i < 4; i++) {
        float d = a[i];
        if (c == 0) {
          Sacc[i] = fmaf(ac0, __expf(d), Sacc[i]);
        } else if (c == 1) {
          Sacc[i] = fmaf(ac1, __builtin_amdgcn_rcpf(fmaf(-2.f, d, h1p + kq[i])), Sacc[i]);
        } else if (c == 2) {
          Gg[i] = fmaf(ac2, __expf(fmaf(2.f, d, nh2 - kq[i] + mv[i])), Gg[i]);
        } else if (c == 3) {
          float tt = d + 1.f;
          float x  = fmaf(tt, tt, mv[i]);
          Gg[i] = fmaf(ac3, __expf(x - m3f), Gg[i]);
        } else if (c == 4) {
          Sacc[i] = fmaf(ac4, __expf(__expf(d + fmaf(-0.5f, kq[i], h4h))), Sacc[i]);
        } else {
          float a5 = fmaf(2.f, d, nh5 - kq[i]);
          Sacc[i] = fmaf(ac5, __expf(__cosf(a5) * __expf(a5)), Sacc[i]);
        }
      }
    }
    float4 ov;
    ov.x = fmaf(Ev[0], Sacc[0], Gg[0]);
    ov.y = fmaf(Ev[1], Sacc[1], Gg[1]);
    ov.z = fmaf(Ev[2], Sacc[2], Gg[2]);
    ov.w = fmaf(Ev[3], Sacc[3], Gg[3]);
    *(float4*)(out + (((size_t)g)*L_ + l0 + lc)*S_ + sb) = ov;
  };

  {
    short8 bA[4], bB[4];
    LOADK(0, bA);
    #pragma unroll 1
    for (int st = 0; st < 16; st += 2) {
      LOADK(st + 1, bB);
      SWEEP2(st, bA);
      LOADK((st + 2) & 15, bA);
      SWEEP2(st + 1, bB);
    }
  }
}

// ---------------------------------------------------------------------------
extern "C" void kernel_launch(void* const* d_in, const int* in_sizes, int n_in,
                              void* d_out, int out_size, void* d_ws, size_t ws_size,
                              hipStream_t stream) {
  (void)in_sizes; (void)n_in; (void)out_size; (void)ws_size;
  const float* q    = (const float*)d_in[0];
  const float* key  = (const float*)d_in[1];
  const float* mask = (const float*)d_in[2];
  const float* klen = (const float*)d_in[3];
  const float* M    = (const float*)d_in[4];
  const float* C    = (const float*)d_in[5];
  char* ws = (char*)d_ws;
  __hip_bfloat16* Ahat = (__hip_bfloat16*)(ws + AHAT_OFF);
  __hip_bfloat16* Khat = (__hip_bfloat16*)(ws + KHAT_OFF);
  float* pi_t    = (float*)(ws + PI_OFF);
  float* hsq     = (float*)(ws + HSQ_OFF);
  float* ksq     = (float*)(ws + KSQ_OFF);
  float* out = (float*)d_out;

  k_prep<<<1088, 256, 52224, stream>>>(q, C, key, M, Ahat, hsq, Khat, ksq, pi_t);
  k_main<<<dim3(64, 16), 256, LDS_TOTAL, stream>>>(Ahat, Khat, hsq, ksq, mask, klen,
                                                   pi_t, out);
}